// Round 8
// baseline (918.970 us; speedup 1.0000x reference)
//
#include <hip/hip_runtime.h>

#define HD 1024
#define FD 2816
#define NE 8
#define NT 1024
#define NSLOT (NT * 2)

typedef short short8 __attribute__((ext_vector_type(8)));
typedef short short4v __attribute__((ext_vector_type(4)));
typedef unsigned u32x4 __attribute__((ext_vector_type(4)));
typedef unsigned u32x2 __attribute__((ext_vector_type(2)));
typedef float f32x4 __attribute__((ext_vector_type(4)));
typedef float f32x16 __attribute__((ext_vector_type(16)));

typedef __attribute__((address_space(3))) unsigned lds_u32;
typedef __attribute__((address_space(1))) const unsigned glb_u32;

#define WAITV(N) asm volatile("s_waitcnt vmcnt(" #N ") lgkmcnt(0)" ::: "memory")
#define BARRIER() do { __builtin_amdgcn_s_barrier(); __builtin_amdgcn_sched_barrier(0); } while (0)

__device__ __forceinline__ void glds16(const void* g, void* l) {
  __builtin_amdgcn_global_load_lds((glb_u32*)g, (lds_u32*)l, 16, 0, 0);
}

__device__ __forceinline__ short f2bf(float f) {
  unsigned u = __builtin_bit_cast(unsigned, f);
  u += 0x7FFFu + ((u >> 16) & 1u);   // round-to-nearest-even
  return (short)(u >> 16);
}

// packed fp32 pair -> bf16x2 (RNE), pure bit ops
__device__ __forceinline__ unsigned cvt2(float lo, float hi) {
  unsigned a = __builtin_bit_cast(unsigned, lo);
  unsigned b = __builtin_bit_cast(unsigned, hi);
  a += 0x7FFFu + ((a >> 16) & 1u);
  b += 0x7FFFu + ((b >> 16) & 1u);
  return (a >> 16) | (b & 0xFFFF0000u);
}
__device__ __forceinline__ int imin(int a, int b) { return a < b ? a : b; }

// ---------------- router ----------------------------------------------------
__global__ void router_kernel(const float* __restrict__ x,
                              const float* __restrict__ rw,
                              int* __restrict__ counts,
                              int* __restrict__ tok_i,
                              float* __restrict__ tok_w) {
  const int t = blockIdx.x;
  const int lane = threadIdx.x;
  const float* px = x + (size_t)t * HD;
  float acc[NE];
#pragma unroll
  for (int e = 0; e < NE; e++) acc[e] = 0.f;
  for (int h = lane; h < HD; h += 64) {
    float xv = px[h];
#pragma unroll
    for (int e = 0; e < NE; e++) acc[e] += xv * rw[e * HD + h];
  }
#pragma unroll
  for (int e = 0; e < NE; e++) {
#pragma unroll
    for (int off = 32; off > 0; off >>= 1)
      acc[e] += __shfl_xor(acc[e], off, 64);
  }
  if (lane == 0) {
    float mx = acc[0];
#pragma unroll
    for (int e = 1; e < NE; e++) mx = fmaxf(mx, acc[e]);
    float ex[NE];
#pragma unroll
    for (int e = 0; e < NE; e++) ex[e] = __expf(acc[e] - mx);
    int i1 = 0;
#pragma unroll
    for (int e = 1; e < NE; e++) if (ex[e] > ex[i1]) i1 = e;
    int i2 = (i1 == 0) ? 1 : 0;
#pragma unroll
    for (int e = 0; e < NE; e++) if (e != i1 && ex[e] > ex[i2]) i2 = e;
    float inv = 1.f / (ex[i1] + ex[i2]);
    tok_i[t * 2 + 0] = i1; tok_w[t * 2 + 0] = ex[i1] * inv;
    tok_i[t * 2 + 1] = i2; tok_w[t * 2 + 1] = ex[i2] * inv;
    atomicAdd(&counts[i1], 1);
    atomicAdd(&counts[i2], 1);
  }
}

// ---------------- scan ------------------------------------------------------
__global__ void scan_kernel(const int* __restrict__ counts,
                            int* __restrict__ bases,
                            int* __restrict__ cursor) {
  if (threadIdx.x == 0) {
    int s = 0;
    for (int e = 0; e < NE; e++) { bases[e] = s; cursor[e] = s; s += counts[e]; }
    bases[NE] = s;
  }
}

// ---------------- fill ------------------------------------------------------
__global__ void fill_kernel(const int* __restrict__ tok_i,
                            const float* __restrict__ tok_w,
                            int* __restrict__ cursor,
                            int* __restrict__ slot_token,
                            float* __restrict__ slot_w,
                            int* __restrict__ slot_of) {
  int t = blockIdx.x * 256 + threadIdx.x;
  if (t >= NT) return;
#pragma unroll
  for (int k = 0; k < 2; k++) {
    int e = tok_i[t * 2 + k];
    int pos = atomicAdd(&cursor[e], 1);
    slot_token[pos] = t;
    slot_w[pos] = tok_w[t * 2 + k];
    slot_of[t * 2 + k] = pos;
  }
}

// ---------------- gather x -> bf16 xg (linear) ------------------------------
__global__ void gather_kernel(const float* __restrict__ x,
                              const int* __restrict__ slot_token,
                              short* __restrict__ xg) {
  const int slot = blockIdx.x;
  const int tok = slot_token[slot];
  const int t = threadIdx.x;
  f32x4 v = *(const f32x4*)(x + (size_t)tok * HD + t * 4);
  u32x2 s;
  s[0] = cvt2(v[0], v[1]);
  s[1] = cvt2(v[2], v[3]);
  *(u32x2*)&xg[(size_t)slot * HD + t * 4] = s;
}

// ---------------- gate+up grouped GEMM (BM=128 BN=64x2 BK=32, B-in-reg) -----
// grid: (352, 16), block 256 (4 waves 2m x 2n; wave 64x32 per mat)
__global__ __launch_bounds__(256, 4) void gateup_kernel(
    const short* __restrict__ xg, const float* __restrict__ gate_w,
    const float* __restrict__ up_w, const int* __restrict__ bases,
    short* __restrict__ m_out) {
  const int bx = blockIdx.x;
  const int e = bx / 44, nt = bx - e * 44;
  const int b0 = bases[e];
  const int ne = bases[e + 1] - b0;
  const int row0 = blockIdx.y * 128;
  if (row0 >= ne) return;
  const int n0 = nt * 64;

  __shared__ short As[2][4096];   // 8 KB/buf: 128 rows x 32 k, pair-line swz

  const int tid = threadIdx.x;
  const int lane = tid & 63, wid = tid >> 6;
  const int l31 = lane & 31, l5 = lane >> 5;
  const int wm = wid >> 1, wn = wid & 1;

  // A glds sources: 2 chunks/thread, pair-line xor folded into source addr
  const short* asrc[2];
#pragma unroll
  for (int q = 0; q < 2; q++) {
    int i = q * 256 + tid;
    int p = i >> 3, j = i & 7;
    int v = j ^ (p & 7);
    int r = 2 * p + (v >> 2), c = v & 3;
    int slot = b0 + imin(row0 + r, ne - 1);
    asrc[q] = xg + (size_t)slot * HD + c * 8;
  }

  // B fragment sources: lane-coalesced (consecutive cols); 32-bit indices
  const float* Gw = gate_w + (size_t)e * HD * FD;
  const float* Uw = up_w + (size_t)e * HD * FD;
  const unsigned lidx = (unsigned)(l5 * 8) * FD + n0 + wn * 32 + l31;

  f32x16 accG[2], accU[2];
#pragma unroll
  for (int fm = 0; fm < 2; fm++) { accG[fm] = (f32x16)0.f; accU[fm] = (f32x16)0.f; }

  float bvA[32], bvB[32];   // [mat*16 + ks*8 + j]

  auto stageA = [&](int buf, int k0) {
#pragma unroll
    for (int q = 0; q < 2; q++)
      glds16(asrc[q] + k0, &As[buf][(q * 256 + wid * 64) * 8]);
  };
  auto loadB = [&](float (&bv)[32], int k0) {
#pragma unroll
    for (int ks = 0; ks < 2; ks++)
#pragma unroll
      for (int j = 0; j < 8; j++) {
        unsigned idx = lidx + (unsigned)(k0 + ks * 16 + j) * FD;
        bv[ks * 8 + j] = Gw[idx];
        bv[16 + ks * 8 + j] = Uw[idx];
      }
  };
  auto compute = [&](const short* Ab, const float (&bv)[32]) {
#pragma unroll
    for (int ks = 0; ks < 2; ks++) {
      short8 a[2];
#pragma unroll
      for (int fm = 0; fm < 2; fm++) {
        int r = wm * 64 + fm * 32 + l31;
        int p = r >> 1, oct = ks * 2 + l5;
        a[fm] = *(const short8*)(Ab + p * 64 +
                                 ((((r & 1) << 2) | oct) ^ (p & 7)) * 8);
      }
      u32x4 ug, uu;
#pragma unroll
      for (int t2 = 0; t2 < 4; t2++) {
        ug[t2] = cvt2(bv[ks * 8 + 2 * t2], bv[ks * 8 + 2 * t2 + 1]);
        uu[t2] = cvt2(bv[16 + ks * 8 + 2 * t2], bv[16 + ks * 8 + 2 * t2 + 1]);
      }
      short8 bg = __builtin_bit_cast(short8, ug);
      short8 bu = __builtin_bit_cast(short8, uu);
#pragma unroll
      for (int fm = 0; fm < 2; fm++) {
        accG[fm] = __builtin_amdgcn_mfma_f32_32x32x16_bf16(a[fm], bg, accG[fm], 0, 0, 0);
        accU[fm] = __builtin_amdgcn_mfma_f32_32x32x16_bf16(a[fm], bu, accU[fm], 0, 0, 0);
      }
    }
  };

  stageA(0, 0);
  __builtin_amdgcn_sched_barrier(0);
  loadB(bvA, 0);
  WAITV(32); BARRIER();

  const int NTL = HD / 32;   // 32
  for (int t = 0; t < NTL; t += 2) {
    stageA(1, (t + 1) * 32);
    __builtin_amdgcn_sched_barrier(0);
    loadB(bvB, (t + 1) * 32);
    compute(&As[0][0], bvA);
    WAITV(32); BARRIER();
    if (t + 2 < NTL) {
      stageA(0, (t + 2) * 32);
      __builtin_amdgcn_sched_barrier(0);
      loadB(bvA, (t + 2) * 32);
      compute(&As[1][0], bvB);
      WAITV(32); BARRIER();
    } else {
      compute(&As[1][0], bvB);
    }
  }

#pragma unroll
  for (int fm = 0; fm < 2; fm++)
#pragma unroll
    for (int q = 0; q < 16; q++) {
      int r = row0 + wm * 64 + fm * 32 + (q & 3) + 8 * (q >> 2) + 4 * l5;
      if (r < ne) {
        int slot = b0 + r;
        float g = accG[fm][q], u = accU[fm][q];
        float mv = (g / (1.f + __expf(-g))) * u;
        m_out[(size_t)slot * FD + n0 + wn * 32 + l31] = f2bf(mv);
      }
    }
}

// ---------------- down grouped GEMM (BM=64 BN=64 BK=64, B-in-reg) -----------
// grid: (128, 32), block 256 (4 waves 2m x 2n; wave 32x32)
__global__ __launch_bounds__(256, 4) void down_kernel(
    const short* __restrict__ m_in, const float* __restrict__ dw,
    const int* __restrict__ bases, const float* __restrict__ slot_w,
    float* __restrict__ out_slot) {
  const int bx = blockIdx.x;
  const int e = bx >> 4, nt = bx & 15;
  const int b0 = bases[e];
  const int ne = bases[e + 1] - b0;
  const int row0 = blockIdx.y * 64;
  if (row0 >= ne) return;
  const int n0 = nt * 64;

  __shared__ short As[2][4096];   // 8 KB/buf: 64 rows x 64 k (2 k-subtiles)

  const int tid = threadIdx.x;
  const int lane = tid & 63, wid = tid >> 6;
  const int l31 = lane & 31, l5 = lane >> 5;
  const int wm = wid >> 1, wn = wid & 1;

  const short* asrc[2];
#pragma unroll
  for (int q = 0; q < 2; q++) {
    int i = q * 256 + tid;
    int sub = i >> 8, ci = i & 255;
    int p = ci >> 3, j = ci & 7;
    int v = j ^ (p & 7);
    int r = 2 * p + (v >> 2), c = v & 3;
    int slot = b0 + imin(row0 + r, ne - 1);
    asrc[q] = m_in + (size_t)slot * FD + sub * 32 + c * 8;
  }

  const float* Dw = dw + (size_t)e * FD * HD;
  const unsigned lidx = (unsigned)(l5 * 8) * HD + n0 + wn * 32 + l31;

  f32x16 acc = (f32x16)0.f;
  float bvA[32], bvB[32];   // [ks*8 + j]

  auto stageA = [&](int buf, int k0) {
#pragma unroll
    for (int q = 0; q < 2; q++)
      glds16(asrc[q] + k0, &As[buf][(q * 256 + wid * 64) * 8]);
  };
  auto loadB = [&](float (&bv)[32], int k0) {
#pragma unroll
    for (int ks = 0; ks < 4; ks++)
#pragma unroll
      for (int j = 0; j < 8; j++)
        bv[ks * 8 + j] = Dw[lidx + (unsigned)(k0 + ks * 16 + j) * HD];
  };
  auto compute = [&](const short* Ab, const float (&bv)[32]) {
#pragma unroll
    for (int ks = 0; ks < 4; ks++) {
      int sub = ks >> 1, oct = (ks & 1) * 2 + l5;
      int r = wm * 32 + l31, p = r >> 1;
      short8 a = *(const short8*)(Ab + sub * 2048 + p * 64 +
                                  ((((r & 1) << 2) | oct) ^ (p & 7)) * 8);
      u32x4 u;
#pragma unroll
      for (int t2 = 0; t2 < 4; t2++)
        u[t2] = cvt2(bv[ks * 8 + 2 * t2], bv[ks * 8 + 2 * t2 + 1]);
      short8 bf = __builtin_bit_cast(short8, u);
      acc = __builtin_amdgcn_mfma_f32_32x32x16_bf16(a, bf, acc, 0, 0, 0);
    }
  };

  stageA(0, 0);
  __builtin_amdgcn_sched_barrier(0);
  loadB(bvA, 0);
  WAITV(32); BARRIER();

  const int NTL = FD / 64;   // 44
  for (int t = 0; t < NTL; t += 2) {
    stageA(1, (t + 1) * 64);
    __builtin_amdgcn_sched_barrier(0);
    loadB(bvB, (t + 1) * 64);
    compute(&As[0][0], bvA);
    WAITV(32); BARRIER();
    if (t + 2 < NTL) {
      stageA(0, (t + 2) * 64);
      __builtin_amdgcn_sched_barrier(0);
      loadB(bvA, (t + 2) * 64);
      compute(&As[1][0], bvB);
      WAITV(32); BARRIER();
    } else {
      compute(&As[1][0], bvB);
    }
  }

#pragma unroll
  for (int q = 0; q < 16; q++) {
    int r = row0 + wm * 32 + (q & 3) + 8 * (q >> 2) + 4 * l5;
    if (r < ne) {
      int slot = b0 + r;
      out_slot[(size_t)slot * HD + n0 + wn * 32 + l31] = acc[q] * slot_w[slot];
    }
  }
}

// ---------------- combine ---------------------------------------------------
__global__ void combine_kernel(const float* __restrict__ out_slot,
                               const int* __restrict__ slot_of,
                               float* __restrict__ out) {
  const int t = blockIdx.x;
  const int s0 = slot_of[t * 2];
  const int s1 = slot_of[t * 2 + 1];
  const int i = threadIdx.x * 4;
  f32x4 a = *(const f32x4*)(out_slot + (size_t)s0 * HD + i);
  f32x4 b = *(const f32x4*)(out_slot + (size_t)s1 * HD + i);
  f32x4 c = a + b;
  *(f32x4*)(out + (size_t)t * HD + i) = c;
}

extern "C" void kernel_launch(void* const* d_in, const int* in_sizes, int n_in,
                              void* d_out, int out_size, void* d_ws,
                              size_t ws_size, hipStream_t stream) {
  const float* x = (const float*)d_in[0];
  const float* rw = (const float*)d_in[1];
  const float* gw = (const float*)d_in[2];
  const float* uw = (const float*)d_in[3];
  const float* dw = (const float*)d_in[4];
  float* out = (float*)d_out;

  char* ws = (char*)d_ws;
  int* counts = (int*)(ws + 0);
  int* cursor = (int*)(ws + 64);
  int* bases = (int*)(ws + 128);
  int* tok_i = (int*)(ws + 256);
  float* tok_w = (float*)(ws + 8448);
  int* slot_token = (int*)(ws + 16640);
  float* slot_w = (float*)(ws + 24832);
  int* slot_of = (int*)(ws + 33024);
  short* xg = (short*)(ws + 41216);             // 2048 x 1024 bf16
  short* m_buf = (short*)(ws + 4235520);        // 2048 x 2816 bf16
  float* out_slot = (float*)(ws + 15769856);    // 2048 x 1024 f32

  (void)hipMemsetAsync(counts, 0, 64, stream);
  router_kernel<<<NT, 64, 0, stream>>>(x, rw, counts, tok_i, tok_w);
  scan_kernel<<<1, 64, 0, stream>>>(counts, bases, cursor);
  fill_kernel<<<NT / 256, 256, 0, stream>>>(tok_i, tok_w, cursor, slot_token,
                                            slot_w, slot_of);
  gather_kernel<<<NSLOT, 256, 0, stream>>>(x, slot_token, xg);
  gateup_kernel<<<dim3(352, 16), 256, 0, stream>>>(xg, gw, uw, bases, m_buf);
  down_kernel<<<dim3(128, 32), 256, 0, stream>>>(m_buf, dw, bases, slot_w,
                                                 out_slot);
  combine_kernel<<<NT, 256, 0, stream>>>(out_slot, slot_of, out);
}

// Round 9
// 214.594 us; speedup vs baseline: 4.2824x; 4.2824x over previous
//
#include <hip/hip_runtime.h>

#define HD 1024
#define FD 2816
#define NE 8
#define NT 1024
#define NSLOT (NT * 2)

typedef short short8 __attribute__((ext_vector_type(8)));
typedef short short4v __attribute__((ext_vector_type(4)));
typedef unsigned u32x4 __attribute__((ext_vector_type(4)));
typedef unsigned u32x2 __attribute__((ext_vector_type(2)));
typedef float f32x4 __attribute__((ext_vector_type(4)));
typedef float f32x16 __attribute__((ext_vector_type(16)));

typedef __attribute__((address_space(3))) unsigned lds_u32;
typedef __attribute__((address_space(1))) const unsigned glb_u32;

#define WAITV(N) asm volatile("s_waitcnt vmcnt(" #N ") lgkmcnt(0)" ::: "memory")
#define BARRIER() do { __builtin_amdgcn_s_barrier(); __builtin_amdgcn_sched_barrier(0); } while (0)

__device__ __forceinline__ void glds16(const void* g, void* l) {
  __builtin_amdgcn_global_load_lds((glb_u32*)g, (lds_u32*)l, 16, 0, 0);
}

__device__ __forceinline__ short f2bf(float f) {
  unsigned u = __builtin_bit_cast(unsigned, f);
  u += 0x7FFFu + ((u >> 16) & 1u);   // round-to-nearest-even
  return (short)(u >> 16);
}

// hardware packed convert: D[15:0]=bf16(lo), D[31:16]=bf16(hi)
__device__ __forceinline__ unsigned cvtpk(float lo, float hi) {
  unsigned r;
  asm("v_cvt_pk_bf16_f32 %0, %1, %2" : "=v"(r) : "v"(lo), "v"(hi));
  return r;
}
__device__ __forceinline__ int imin(int a, int b) { return a < b ? a : b; }

// ---------------- router ----------------------------------------------------
__global__ void router_kernel(const float* __restrict__ x,
                              const float* __restrict__ rw,
                              int* __restrict__ counts,
                              int* __restrict__ tok_i,
                              float* __restrict__ tok_w) {
  const int t = blockIdx.x;
  const int lane = threadIdx.x;
  const float* px = x + (size_t)t * HD;
  float acc[NE];
#pragma unroll
  for (int e = 0; e < NE; e++) acc[e] = 0.f;
  for (int h = lane; h < HD; h += 64) {
    float xv = px[h];
#pragma unroll
    for (int e = 0; e < NE; e++) acc[e] += xv * rw[e * HD + h];
  }
#pragma unroll
  for (int e = 0; e < NE; e++) {
#pragma unroll
    for (int off = 32; off > 0; off >>= 1)
      acc[e] += __shfl_xor(acc[e], off, 64);
  }
  if (lane == 0) {
    float mx = acc[0];
#pragma unroll
    for (int e = 1; e < NE; e++) mx = fmaxf(mx, acc[e]);
    float ex[NE];
#pragma unroll
    for (int e = 0; e < NE; e++) ex[e] = __expf(acc[e] - mx);
    int i1 = 0;
#pragma unroll
    for (int e = 1; e < NE; e++) if (ex[e] > ex[i1]) i1 = e;
    int i2 = (i1 == 0) ? 1 : 0;
#pragma unroll
    for (int e = 0; e < NE; e++) if (e != i1 && ex[e] > ex[i2]) i2 = e;
    float inv = 1.f / (ex[i1] + ex[i2]);
    tok_i[t * 2 + 0] = i1; tok_w[t * 2 + 0] = ex[i1] * inv;
    tok_i[t * 2 + 1] = i2; tok_w[t * 2 + 1] = ex[i2] * inv;
    atomicAdd(&counts[i1], 1);
    atomicAdd(&counts[i2], 1);
  }
}

// ---------------- scan ------------------------------------------------------
__global__ void scan_kernel(const int* __restrict__ counts,
                            int* __restrict__ bases,
                            int* __restrict__ cursor) {
  if (threadIdx.x == 0) {
    int s = 0;
    for (int e = 0; e < NE; e++) { bases[e] = s; cursor[e] = s; s += counts[e]; }
    bases[NE] = s;
  }
}

// ---------------- fill ------------------------------------------------------
__global__ void fill_kernel(const int* __restrict__ tok_i,
                            const float* __restrict__ tok_w,
                            int* __restrict__ cursor,
                            int* __restrict__ slot_token,
                            float* __restrict__ slot_w,
                            int* __restrict__ slot_of) {
  int t = blockIdx.x * 256 + threadIdx.x;
  if (t >= NT) return;
#pragma unroll
  for (int k = 0; k < 2; k++) {
    int e = tok_i[t * 2 + k];
    int pos = atomicAdd(&cursor[e], 1);
    slot_token[pos] = t;
    slot_w[pos] = tok_w[t * 2 + k];
    slot_of[t * 2 + k] = pos;
  }
}

// ---------------- gather x -> bf16 xg (linear) ------------------------------
__global__ void gather_kernel(const float* __restrict__ x,
                              const int* __restrict__ slot_token,
                              short* __restrict__ xg) {
  const int slot = blockIdx.x;
  const int tok = slot_token[slot];
  const int t = threadIdx.x;
  f32x4 v = *(const f32x4*)(x + (size_t)tok * HD + t * 4);
  u32x2 s;
  s[0] = cvtpk(v[0], v[1]);
  s[1] = cvtpk(v[2], v[3]);
  *(u32x2*)&xg[(size_t)slot * HD + t * 4] = s;
}

// ============ gate+up grouped GEMM (BM=128 BN=64x2 BK=32, B-in-reg) =========
// grid: (352, 16), block 256 (4 waves 2m x 2n; wave 64x32 per mat)

#define GU_STAGEA(buf, k0) do {                                    \
    glds16(asrc[0] + (k0), &As[buf][wid * 512]);                   \
    glds16(asrc[1] + (k0), &As[buf][2048 + wid * 512]);            \
  } while (0)

#define GU_LOADB(G, U, k0) do {                                    \
    _Pragma("unroll")                                              \
    for (int ks = 0; ks < 2; ks++) {                               \
      _Pragma("unroll")                                            \
      for (int j = 0; j < 8; j++) {                                \
        unsigned idx = lidx + (unsigned)((k0) + ks * 16 + j) * FD; \
        G[ks * 8 + j] = Gw[idx];                                   \
        U[ks * 8 + j] = Uw[idx];                                   \
      }                                                            \
    }                                                              \
  } while (0)

#define GU_COMPUTE(Ab, G, U) do {                                             \
    _Pragma("unroll")                                                         \
    for (int ks = 0; ks < 2; ks++) {                                          \
      const int oct = ks * 2 + l5;                                            \
      short8 a0, a1;                                                          \
      { int r = wm * 64 + l31, p = r >> 1;                                    \
        a0 = *(const short8*)((Ab) + p * 64 +                                 \
              ((((r & 1) << 2) | oct) ^ (p & 7)) * 8); }                      \
      { int r = wm * 64 + 32 + l31, p = r >> 1;                               \
        a1 = *(const short8*)((Ab) + p * 64 +                                 \
              ((((r & 1) << 2) | oct) ^ (p & 7)) * 8); }                      \
      u32x4 ug, uu;                                                           \
      _Pragma("unroll")                                                       \
      for (int t2 = 0; t2 < 4; t2++) {                                        \
        ug[t2] = cvtpk(G[ks * 8 + 2 * t2], G[ks * 8 + 2 * t2 + 1]);           \
        uu[t2] = cvtpk(U[ks * 8 + 2 * t2], U[ks * 8 + 2 * t2 + 1]);           \
      }                                                                       \
      short8 bg = __builtin_bit_cast(short8, ug);                             \
      short8 bu = __builtin_bit_cast(short8, uu);                             \
      accG0 = __builtin_amdgcn_mfma_f32_32x32x16_bf16(a0, bg, accG0, 0, 0, 0);\
      accU0 = __builtin_amdgcn_mfma_f32_32x32x16_bf16(a0, bu, accU0, 0, 0, 0);\
      accG1 = __builtin_amdgcn_mfma_f32_32x32x16_bf16(a1, bg, accG1, 0, 0, 0);\
      accU1 = __builtin_amdgcn_mfma_f32_32x32x16_bf16(a1, bu, accU1, 0, 0, 0);\
    }                                                                         \
  } while (0)

__global__ __launch_bounds__(256, 2) void gateup_kernel(
    const short* __restrict__ xg, const float* __restrict__ gate_w,
    const float* __restrict__ up_w, const int* __restrict__ bases,
    short* __restrict__ m_out) {
  const int bx = blockIdx.x;
  const int e = bx / 44, nt = bx - e * 44;
  const int b0 = bases[e];
  const int ne = bases[e + 1] - b0;
  const int row0 = blockIdx.y * 128;
  if (row0 >= ne) return;
  const int n0 = nt * 64;

  __shared__ short As[2][4096];   // 8 KB/buf: 128 rows x 32 k, pair-line swz

  const int tid = threadIdx.x;
  const int lane = tid & 63, wid = tid >> 6;
  const int l31 = lane & 31, l5 = lane >> 5;
  const int wm = wid >> 1, wn = wid & 1;

  const short* asrc[2];
#pragma unroll
  for (int q = 0; q < 2; q++) {
    int i = q * 256 + tid;
    int p = i >> 3, j = i & 7;
    int v = j ^ (p & 7);
    int r = 2 * p + (v >> 2), c = v & 3;
    int slot = b0 + imin(row0 + r, ne - 1);
    asrc[q] = xg + (size_t)slot * HD + c * 8;
  }

  const float* Gw = gate_w + (size_t)e * HD * FD;
  const float* Uw = up_w + (size_t)e * HD * FD;
  const unsigned lidx = (unsigned)(l5 * 8) * FD + n0 + wn * 32 + l31;

  f32x16 accG0 = (f32x16)0.f, accG1 = (f32x16)0.f;
  f32x16 accU0 = (f32x16)0.f, accU1 = (f32x16)0.f;
  f32x16 bvAG, bvAU, bvBG, bvBU;

  GU_STAGEA(0, 0);
  __builtin_amdgcn_sched_barrier(0);
  GU_LOADB(bvAG, bvAU, 0);
  WAITV(32); BARRIER();

  for (int t = 0; t < 32; t += 2) {
    GU_STAGEA(1, (t + 1) * 32);
    __builtin_amdgcn_sched_barrier(0);
    GU_LOADB(bvBG, bvBU, (t + 1) * 32);
    GU_COMPUTE(&As[0][0], bvAG, bvAU);
    WAITV(32); BARRIER();
    if (t + 2 < 32) {
      GU_STAGEA(0, (t + 2) * 32);
      __builtin_amdgcn_sched_barrier(0);
      GU_LOADB(bvAG, bvAU, (t + 2) * 32);
      GU_COMPUTE(&As[1][0], bvBG, bvBU);
      WAITV(32); BARRIER();
    } else {
      GU_COMPUTE(&As[1][0], bvBG, bvBU);
    }
  }

#pragma unroll
  for (int q = 0; q < 16; q++) {
    int rb_ = (q & 3) + 8 * (q >> 2) + 4 * l5;
    {
      int r = row0 + wm * 64 + rb_;
      if (r < ne) {
        int slot = b0 + r;
        float g = accG0[q], u = accU0[q];
        float mv = (g / (1.f + __expf(-g))) * u;
        m_out[(size_t)slot * FD + n0 + wn * 32 + l31] = f2bf(mv);
      }
    }
    {
      int r = row0 + wm * 64 + 32 + rb_;
      if (r < ne) {
        int slot = b0 + r;
        float g = accG1[q], u = accU1[q];
        float mv = (g / (1.f + __expf(-g))) * u;
        m_out[(size_t)slot * FD + n0 + wn * 32 + l31] = f2bf(mv);
      }
    }
  }
}

// ============ down grouped GEMM (BM=64 BN=64 BK=64, B-in-reg) ===============
// grid: (128, 32), block 256 (4 waves 2m x 2n; wave 32x32)

#define DW_STAGEA(buf, k0) do {                                    \
    glds16(asrc[0] + (k0), &As[buf][wid * 512]);                   \
    glds16(asrc[1] + (k0), &As[buf][2048 + wid * 512]);            \
  } while (0)

#define DW_LOADB(B0, B1, k0) do {                                  \
    _Pragma("unroll")                                              \
    for (int ks = 0; ks < 4; ks++) {                               \
      _Pragma("unroll")                                            \
      for (int j = 0; j < 8; j++) {                                \
        unsigned idx = lidx + (unsigned)((k0) + ks * 16 + j) * HD; \
        if (ks < 2) B0[ks * 8 + j] = Dw[idx];                      \
        else        B1[(ks - 2) * 8 + j] = Dw[idx];                \
      }                                                            \
    }                                                              \
  } while (0)

#define DW_COMPUTE(Ab, B0, B1) do {                                           \
    _Pragma("unroll")                                                         \
    for (int ks = 0; ks < 4; ks++) {                                          \
      const int sub = ks >> 1, oct = (ks & 1) * 2 + l5;                       \
      int r = wm * 32 + l31, p = r >> 1;                                      \
      short8 a = *(const short8*)((Ab) + sub * 2048 + p * 64 +                \
                  ((((r & 1) << 2) | oct) ^ (p & 7)) * 8);                    \
      u32x4 ub;                                                               \
      _Pragma("unroll")                                                       \
      for (int t2 = 0; t2 < 4; t2++) {                                        \
        if (ks < 2)                                                           \
          ub[t2] = cvtpk(B0[ks * 8 + 2 * t2], B0[ks * 8 + 2 * t2 + 1]);       \
        else                                                                  \
          ub[t2] = cvtpk(B1[(ks - 2) * 8 + 2 * t2],                           \
                         B1[(ks - 2) * 8 + 2 * t2 + 1]);                      \
      }                                                                       \
      short8 bf = __builtin_bit_cast(short8, ub);                             \
      acc = __builtin_amdgcn_mfma_f32_32x32x16_bf16(a, bf, acc, 0, 0, 0);     \
    }                                                                         \
  } while (0)

__global__ __launch_bounds__(256, 3) void down_kernel(
    const short* __restrict__ m_in, const float* __restrict__ dw,
    const int* __restrict__ bases, const float* __restrict__ slot_w,
    float* __restrict__ out_slot) {
  const int bx = blockIdx.x;
  const int e = bx >> 4, nt = bx & 15;
  const int b0 = bases[e];
  const int ne = bases[e + 1] - b0;
  const int row0 = blockIdx.y * 64;
  if (row0 >= ne) return;
  const int n0 = nt * 64;

  __shared__ short As[2][4096];   // 8 KB/buf: 64 rows x 64 k (2 k-subtiles)

  const int tid = threadIdx.x;
  const int lane = tid & 63, wid = tid >> 6;
  const int l31 = lane & 31, l5 = lane >> 5;
  const int wm = wid >> 1, wn = wid & 1;

  const short* asrc[2];
#pragma unroll
  for (int q = 0; q < 2; q++) {
    int i = q * 256 + tid;
    int sub = i >> 8, ci = i & 255;
    int p = ci >> 3, j = ci & 7;
    int v = j ^ (p & 7);
    int r = 2 * p + (v >> 2), c = v & 3;
    int slot = b0 + imin(row0 + r, ne - 1);
    asrc[q] = m_in + (size_t)slot * FD + sub * 32 + c * 8;
  }

  const float* Dw = dw + (size_t)e * FD * HD;
  const unsigned lidx = (unsigned)(l5 * 8) * HD + n0 + wn * 32 + l31;

  f32x16 acc = (f32x16)0.f;
  f32x16 bvA0, bvA1, bvB0, bvB1;

  DW_STAGEA(0, 0);
  __builtin_amdgcn_sched_barrier(0);
  DW_LOADB(bvA0, bvA1, 0);
  WAITV(32); BARRIER();

  const int NTL = FD / 64;   // 44
  for (int t = 0; t < NTL; t += 2) {
    DW_STAGEA(1, (t + 1) * 64);
    __builtin_amdgcn_sched_barrier(0);
    DW_LOADB(bvB0, bvB1, (t + 1) * 64);
    DW_COMPUTE(&As[0][0], bvA0, bvA1);
    WAITV(32); BARRIER();
    if (t + 2 < NTL) {
      DW_STAGEA(0, (t + 2) * 64);
      __builtin_amdgcn_sched_barrier(0);
      DW_LOADB(bvA0, bvA1, (t + 2) * 64);
      DW_COMPUTE(&As[1][0], bvB0, bvB1);
      WAITV(32); BARRIER();
    } else {
      DW_COMPUTE(&As[1][0], bvB0, bvB1);
    }
  }

#pragma unroll
  for (int q = 0; q < 16; q++) {
    int r = row0 + wm * 32 + (q & 3) + 8 * (q >> 2) + 4 * l5;
    if (r < ne) {
      int slot = b0 + r;
      out_slot[(size_t)slot * HD + n0 + wn * 32 + l31] = acc[q] * slot_w[slot];
    }
  }
}

// ---------------- combine ---------------------------------------------------
__global__ void combine_kernel(const float* __restrict__ out_slot,
                               const int* __restrict__ slot_of,
                               float* __restrict__ out) {
  const int t = blockIdx.x;
  const int s0 = slot_of[t * 2];
  const int s1 = slot_of[t * 2 + 1];
  const int i = threadIdx.x * 4;
  f32x4 a = *(const f32x4*)(out_slot + (size_t)s0 * HD + i);
  f32x4 b = *(const f32x4*)(out_slot + (size_t)s1 * HD + i);
  f32x4 c = a + b;
  *(f32x4*)(out + (size_t)t * HD + i) = c;
}

extern "C" void kernel_launch(void* const* d_in, const int* in_sizes, int n_in,
                              void* d_out, int out_size, void* d_ws,
                              size_t ws_size, hipStream_t stream) {
  const float* x = (const float*)d_in[0];
  const float* rw = (const float*)d_in[1];
  const float* gw = (const float*)d_in[2];
  const float* uw = (const float*)d_in[3];
  const float* dw = (const float*)d_in[4];
  float* out = (float*)d_out;

  char* ws = (char*)d_ws;
  int* counts = (int*)(ws + 0);
  int* cursor = (int*)(ws + 64);
  int* bases = (int*)(ws + 128);
  int* tok_i = (int*)(ws + 256);
  float* tok_w = (float*)(ws + 8448);
  int* slot_token = (int*)(ws + 16640);
  float* slot_w = (float*)(ws + 24832);
  int* slot_of = (int*)(ws + 33024);
  short* xg = (short*)(ws + 41216);             // 2048 x 1024 bf16
  short* m_buf = (short*)(ws + 4235520);        // 2048 x 2816 bf16
  float* out_slot = (float*)(ws + 15769856);    // 2048 x 1024 f32

  (void)hipMemsetAsync(counts, 0, 64, stream);
  router_kernel<<<NT, 64, 0, stream>>>(x, rw, counts, tok_i, tok_w);
  scan_kernel<<<1, 64, 0, stream>>>(counts, bases, cursor);
  fill_kernel<<<NT / 256, 256, 0, stream>>>(tok_i, tok_w, cursor, slot_token,
                                            slot_w, slot_of);
  gather_kernel<<<NSLOT, 256, 0, stream>>>(x, slot_token, xg);
  gateup_kernel<<<dim3(352, 16), 256, 0, stream>>>(xg, gw, uw, bases, m_buf);
  down_kernel<<<dim3(128, 32), 256, 0, stream>>>(m_buf, dw, bases, slot_w,
                                                 out_slot);
  combine_kernel<<<NT, 256, 0, stream>>>(out_slot, slot_of, out);
}

// Round 11
// 203.865 us; speedup vs baseline: 4.5077x; 1.0526x over previous
//
#include <hip/hip_runtime.h>

#define HD 1024
#define FD 2816
#define NE 8
#define NT 1024
#define NSLOT (NT * 2)

typedef short short8 __attribute__((ext_vector_type(8)));
typedef unsigned u32x4 __attribute__((ext_vector_type(4)));
typedef unsigned u32x2 __attribute__((ext_vector_type(2)));
typedef float f32x4 __attribute__((ext_vector_type(4)));
typedef float f32x16 __attribute__((ext_vector_type(16)));

typedef __attribute__((address_space(3))) unsigned lds_u32;
typedef __attribute__((address_space(1))) const unsigned glb_u32;

#define WAITV(N) asm volatile("s_waitcnt vmcnt(" #N ") lgkmcnt(0)" ::: "memory")
#define BARRIER() do { __builtin_amdgcn_s_barrier(); __builtin_amdgcn_sched_barrier(0); } while (0)
#define SB() __builtin_amdgcn_sched_barrier(0)

__device__ __forceinline__ void glds16(const void* g, void* l) {
  __builtin_amdgcn_global_load_lds((glb_u32*)g, (lds_u32*)l, 16, 0, 0);
}

__device__ __forceinline__ short f2bf(float f) {
  unsigned u = __builtin_bit_cast(unsigned, f);
  u += 0x7FFFu + ((u >> 16) & 1u);   // round-to-nearest-even
  return (short)(u >> 16);
}

// hardware packed convert: D[15:0]=bf16(lo), D[31:16]=bf16(hi)
__device__ __forceinline__ unsigned cvtpk(float lo, float hi) {
  unsigned r;
  asm("v_cvt_pk_bf16_f32 %0, %1, %2" : "=v"(r) : "v"(lo), "v"(hi));
  return r;
}
__device__ __forceinline__ int imin(int a, int b) { return a < b ? a : b; }

// ---------------- router ----------------------------------------------------
__global__ void router_kernel(const float* __restrict__ x,
                              const float* __restrict__ rw,
                              int* __restrict__ counts,
                              int* __restrict__ tok_i,
                              float* __restrict__ tok_w) {
  const int t = blockIdx.x;
  const int lane = threadIdx.x;
  const float* px = x + (size_t)t * HD;
  float acc[NE];
#pragma unroll
  for (int e = 0; e < NE; e++) acc[e] = 0.f;
  for (int h = lane; h < HD; h += 64) {
    float xv = px[h];
#pragma unroll
    for (int e = 0; e < NE; e++) acc[e] += xv * rw[e * HD + h];
  }
#pragma unroll
  for (int e = 0; e < NE; e++) {
#pragma unroll
    for (int off = 32; off > 0; off >>= 1)
      acc[e] += __shfl_xor(acc[e], off, 64);
  }
  if (lane == 0) {
    float mx = acc[0];
#pragma unroll
    for (int e = 1; e < NE; e++) mx = fmaxf(mx, acc[e]);
    float ex[NE];
#pragma unroll
    for (int e = 0; e < NE; e++) ex[e] = __expf(acc[e] - mx);
    int i1 = 0;
#pragma unroll
    for (int e = 1; e < NE; e++) if (ex[e] > ex[i1]) i1 = e;
    int i2 = (i1 == 0) ? 1 : 0;
#pragma unroll
    for (int e = 0; e < NE; e++) if (e != i1 && ex[e] > ex[i2]) i2 = e;
    float inv = 1.f / (ex[i1] + ex[i2]);
    tok_i[t * 2 + 0] = i1; tok_w[t * 2 + 0] = ex[i1] * inv;
    tok_i[t * 2 + 1] = i2; tok_w[t * 2 + 1] = ex[i2] * inv;
    atomicAdd(&counts[i1], 1);
    atomicAdd(&counts[i2], 1);
  }
}

// ---------------- scan ------------------------------------------------------
__global__ void scan_kernel(const int* __restrict__ counts,
                            int* __restrict__ bases,
                            int* __restrict__ cursor) {
  if (threadIdx.x == 0) {
    int s = 0;
    for (int e = 0; e < NE; e++) { bases[e] = s; cursor[e] = s; s += counts[e]; }
    bases[NE] = s;
  }
}

// ---------------- fill ------------------------------------------------------
__global__ void fill_kernel(const int* __restrict__ tok_i,
                            const float* __restrict__ tok_w,
                            int* __restrict__ cursor,
                            int* __restrict__ slot_token,
                            float* __restrict__ slot_w,
                            int* __restrict__ slot_of) {
  int t = blockIdx.x * 256 + threadIdx.x;
  if (t >= NT) return;
#pragma unroll
  for (int k = 0; k < 2; k++) {
    int e = tok_i[t * 2 + k];
    int pos = atomicAdd(&cursor[e], 1);
    slot_token[pos] = t;
    slot_w[pos] = tok_w[t * 2 + k];
    slot_of[t * 2 + k] = pos;
  }
}

// ---------------- gather x -> bf16 xg (linear) ------------------------------
__global__ void gather_kernel(const float* __restrict__ x,
                              const int* __restrict__ slot_token,
                              short* __restrict__ xg) {
  const int slot = blockIdx.x;
  const int tok = slot_token[slot];
  const int t = threadIdx.x;
  f32x4 v = *(const f32x4*)(x + (size_t)tok * HD + t * 4);
  u32x2 s;
  s[0] = cvtpk(v[0], v[1]);
  s[1] = cvtpk(v[2], v[3]);
  *(u32x2*)&xg[(size_t)slot * HD + t * 4] = s;
}

// ============ gate+up grouped GEMM (BM=128 BN=64x2 BK=32, 3-deep pipe) ======
// grid: (352, 16), block 256 (4 waves 2m x 2n; wave 64x32 per mat)

#define GU_STAGEA(S, koff) do {                                    \
    glds16(asrc[0] + (koff), &As[S][wid * 512]);                   \
    glds16(asrc[1] + (koff), &As[S][2048 + wid * 512]);            \
  } while (0)

#define GU_LOADB(G, U, k0) do {                                    \
    _Pragma("unroll")                                              \
    for (int ks = 0; ks < 2; ks++) {                               \
      _Pragma("unroll")                                            \
      for (int j = 0; j < 8; j++) {                                \
        unsigned idx = lidx + (unsigned)((k0) + ks * 16 + j) * FD; \
        G[ks * 8 + j] = Gw[idx];                                   \
        U[ks * 8 + j] = Uw[idx];                                   \
      }                                                            \
    }                                                              \
  } while (0)

#define GU_COMPUTE(Ab, G, U) do {                                             \
    _Pragma("unroll")                                                         \
    for (int ks = 0; ks < 2; ks++) {                                          \
      const int oct = ks * 2 + l5;                                            \
      short8 a0, a1;                                                          \
      { int r = wm * 64 + l31, p = r >> 1;                                    \
        a0 = *(const short8*)((Ab) + p * 64 +                                 \
              ((((r & 1) << 2) | oct) ^ (p & 7)) * 8); }                      \
      { int r = wm * 64 + 32 + l31, p = r >> 1;                               \
        a1 = *(const short8*)((Ab) + p * 64 +                                 \
              ((((r & 1) << 2) | oct) ^ (p & 7)) * 8); }                      \
      u32x4 ug, uu;                                                           \
      _Pragma("unroll")                                                       \
      for (int t2 = 0; t2 < 4; t2++) {                                        \
        ug[t2] = cvtpk(G[ks * 8 + 2 * t2], G[ks * 8 + 2 * t2 + 1]);           \
        uu[t2] = cvtpk(U[ks * 8 + 2 * t2], U[ks * 8 + 2 * t2 + 1]);           \
      }                                                                       \
      short8 bg = __builtin_bit_cast(short8, ug);                             \
      short8 bu = __builtin_bit_cast(short8, uu);                             \
      accG0 = __builtin_amdgcn_mfma_f32_32x32x16_bf16(a0, bg, accG0, 0, 0, 0);\
      accU0 = __builtin_amdgcn_mfma_f32_32x32x16_bf16(a0, bu, accU0, 0, 0, 0);\
      accG1 = __builtin_amdgcn_mfma_f32_32x32x16_bf16(a1, bg, accG1, 0, 0, 0);\
      accU1 = __builtin_amdgcn_mfma_f32_32x32x16_bf16(a1, bu, accU1, 0, 0, 0);\
    }                                                                         \
  } while (0)

// one steady-state iteration: compute tile T (slot S), stage tile T+3 into S
// vmcnt cap is 63 (6-bit): drains t+1's 34-group fully + 5 of t+2 (harmless)
#define GU_ITER(S, T) do {                       \
    GU_COMPUTE(&As[S][0], bG##S, bU##S);         \
    BARRIER();                                   \
    GU_STAGEA(S, ((T) + 3) * 32);                \
    SB();                                        \
    GU_LOADB(bG##S, bU##S, ((T) + 3) * 32);      \
    WAITV(63);                                   \
    BARRIER();                                   \
  } while (0)

__global__ __launch_bounds__(256, 2) void gateup_kernel(
    const short* __restrict__ xg, const float* __restrict__ gate_w,
    const float* __restrict__ up_w, const int* __restrict__ bases,
    short* __restrict__ m_out) {
  const int bx = blockIdx.x;
  const int e = bx / 44, nt = bx - e * 44;
  const int b0 = bases[e];
  const int ne = bases[e + 1] - b0;
  const int row0 = blockIdx.y * 128;
  if (row0 >= ne) return;
  const int n0 = nt * 64;

  __shared__ short As[3][4096];   // 8 KB/buf: 128 rows x 32 k, pair-line swz

  const int tid = threadIdx.x;
  const int lane = tid & 63, wid = tid >> 6;
  const int l31 = lane & 31, l5 = lane >> 5;
  const int wm = wid >> 1, wn = wid & 1;

  const short* asrc[2];
#pragma unroll
  for (int q = 0; q < 2; q++) {
    int i = q * 256 + tid;
    int p = i >> 3, j = i & 7;
    int v = j ^ (p & 7);
    int r = 2 * p + (v >> 2), c = v & 3;
    int slot = b0 + imin(row0 + r, ne - 1);
    asrc[q] = xg + (size_t)slot * HD + c * 8;
  }

  const float* Gw = gate_w + (size_t)e * HD * FD;
  const float* Uw = up_w + (size_t)e * HD * FD;
  const unsigned lidx = (unsigned)(l5 * 8) * FD + n0 + wn * 32 + l31;

  f32x16 accG0 = (f32x16)0.f, accG1 = (f32x16)0.f;
  f32x16 accU0 = (f32x16)0.f, accU1 = (f32x16)0.f;
  f32x16 bG0, bU0, bG1, bU1, bG2, bU2;

  // prologue: 3 tiles in flight
  GU_STAGEA(0, 0);  SB(); GU_LOADB(bG0, bU0, 0);  SB();
  GU_STAGEA(1, 32); SB(); GU_LOADB(bG1, bU1, 32); SB();
  GU_STAGEA(2, 64); SB(); GU_LOADB(bG2, bU2, 64);
  WAITV(63);   // tile0 (34-group) fully landed; tiles 1,2 mostly in flight
  BARRIER();

  // NTL = 32 tiles: main computes 0..28, stages 3..31
  for (int t = 0; t < 27; t += 3) {
    GU_ITER(0, t);
    GU_ITER(1, t + 1);
    GU_ITER(2, t + 2);
  }
  GU_ITER(0, 27);
  GU_ITER(1, 28);
  GU_COMPUTE(&As[2][0], bG2, bU2);  // t=29
  WAITV(34); BARRIER();
  GU_COMPUTE(&As[0][0], bG0, bU0);  // t=30
  WAITV(0); BARRIER();
  GU_COMPUTE(&As[1][0], bG1, bU1);  // t=31

#pragma unroll
  for (int q = 0; q < 16; q++) {
    int rb_ = (q & 3) + 8 * (q >> 2) + 4 * l5;
    {
      int r = row0 + wm * 64 + rb_;
      if (r < ne) {
        int slot = b0 + r;
        float g = accG0[q], u = accU0[q];
        float mv = (g / (1.f + __expf(-g))) * u;
        m_out[(size_t)slot * FD + n0 + wn * 32 + l31] = f2bf(mv);
      }
    }
    {
      int r = row0 + wm * 64 + 32 + rb_;
      if (r < ne) {
        int slot = b0 + r;
        float g = accG1[q], u = accU1[q];
        float mv = (g / (1.f + __expf(-g))) * u;
        m_out[(size_t)slot * FD + n0 + wn * 32 + l31] = f2bf(mv);
      }
    }
  }
}

// ============ down grouped GEMM (BM=64 BN=64 BK=32, 3-deep pipe) ============
// grid: (128, 32), block 256 (4 waves 2m x 2n; wave 32x32)

#define DW_STAGEA(S, koff) glds16(asrc + (koff), &As[S][wid * 512])

#define DW_LOADB(B, k0) do {                                       \
    _Pragma("unroll")                                              \
    for (int ks = 0; ks < 2; ks++) {                               \
      _Pragma("unroll")                                            \
      for (int j = 0; j < 8; j++) {                                \
        unsigned idx = lidx + (unsigned)((k0) + ks * 16 + j) * HD; \
        B[ks * 8 + j] = Dw[idx];                                   \
      }                                                            \
    }                                                              \
  } while (0)

#define DW_COMPUTE(Ab, B) do {                                                \
    _Pragma("unroll")                                                         \
    for (int ks = 0; ks < 2; ks++) {                                          \
      const int oct = ks * 2 + l5;                                            \
      int r = wm * 32 + l31, p = r >> 1;                                      \
      short8 a = *(const short8*)((Ab) + p * 64 +                             \
                  ((((r & 1) << 2) | oct) ^ (p & 7)) * 8);                    \
      u32x4 ub;                                                               \
      _Pragma("unroll")                                                       \
      for (int t2 = 0; t2 < 4; t2++)                                          \
        ub[t2] = cvtpk(B[ks * 8 + 2 * t2], B[ks * 8 + 2 * t2 + 1]);           \
      short8 bf = __builtin_bit_cast(short8, ub);                             \
      acc = __builtin_amdgcn_mfma_f32_32x32x16_bf16(a, bf, acc, 0, 0, 0);     \
    }                                                                         \
  } while (0)

#define DW_ITER(S, T) do {                       \
    DW_COMPUTE(&As[S][0], bv##S);                \
    BARRIER();                                   \
    DW_STAGEA(S, ((T) + 3) * 32);                \
    SB();                                        \
    DW_LOADB(bv##S, ((T) + 3) * 32);             \
    WAITV(34);                                   \
    BARRIER();                                   \
  } while (0)

__global__ __launch_bounds__(256, 3) void down_kernel(
    const short* __restrict__ m_in, const float* __restrict__ dw,
    const int* __restrict__ bases, const float* __restrict__ slot_w,
    float* __restrict__ out_slot) {
  const int bx = blockIdx.x;
  const int e = bx >> 4, nt = bx & 15;
  const int b0 = bases[e];
  const int ne = bases[e + 1] - b0;
  const int row0 = blockIdx.y * 64;
  if (row0 >= ne) return;
  const int n0 = nt * 64;

  __shared__ short As[3][2048];   // 4 KB/buf: 64 rows x 32 k, pair-line swz

  const int tid = threadIdx.x;
  const int lane = tid & 63, wid = tid >> 6;
  const int l31 = lane & 31, l5 = lane >> 5;
  const int wm = wid >> 1, wn = wid & 1;

  const short* asrc;
  {
    int p = tid >> 3, j = tid & 7;
    int v = j ^ (p & 7);
    int r = 2 * p + (v >> 2), c = v & 3;
    int slot = b0 + imin(row0 + r, ne - 1);
    asrc = m_in + (size_t)slot * FD + c * 8;
  }

  const float* Dw = dw + (size_t)e * FD * HD;
  const unsigned lidx = (unsigned)(l5 * 8) * HD + n0 + wn * 32 + l31;

  f32x16 acc = (f32x16)0.f;
  f32x16 bv0, bv1, bv2;

  DW_STAGEA(0, 0);  SB(); DW_LOADB(bv0, 0);  SB();
  DW_STAGEA(1, 32); SB(); DW_LOADB(bv1, 32); SB();
  DW_STAGEA(2, 64); SB(); DW_LOADB(bv2, 64);
  WAITV(34);
  BARRIER();

  // NTL = 88 tiles: main computes 0..84, stages 3..87
  for (int t = 0; t < 84; t += 3) {
    DW_ITER(0, t);
    DW_ITER(1, t + 1);
    DW_ITER(2, t + 2);
  }
  DW_ITER(0, 84);
  DW_COMPUTE(&As[1][0], bv1);   // t=85
  WAITV(17); BARRIER();
  DW_COMPUTE(&As[2][0], bv2);   // t=86
  WAITV(0); BARRIER();
  DW_COMPUTE(&As[0][0], bv0);   // t=87

#pragma unroll
  for (int q = 0; q < 16; q++) {
    int r = row0 + wm * 32 + (q & 3) + 8 * (q >> 2) + 4 * l5;
    if (r < ne) {
      int slot = b0 + r;
      out_slot[(size_t)slot * HD + n0 + wn * 32 + l31] = acc[q] * slot_w[slot];
    }
  }
}

// ---------------- combine ---------------------------------------------------
__global__ void combine_kernel(const float* __restrict__ out_slot,
                               const int* __restrict__ slot_of,
                               float* __restrict__ out) {
  const int t = blockIdx.x;
  const int s0 = slot_of[t * 2];
  const int s1 = slot_of[t * 2 + 1];
  const int i = threadIdx.x * 4;
  f32x4 a = *(const f32x4*)(out_slot + (size_t)s0 * HD + i);
  f32x4 b = *(const f32x4*)(out_slot + (size_t)s1 * HD + i);
  f32x4 c = a + b;
  *(f32x4*)(out + (size_t)t * HD + i) = c;
}

extern "C" void kernel_launch(void* const* d_in, const int* in_sizes, int n_in,
                              void* d_out, int out_size, void* d_ws,
                              size_t ws_size, hipStream_t stream) {
  const float* x = (const float*)d_in[0];
  const float* rw = (const float*)d_in[1];
  const float* gw = (const float*)d_in[2];
  const float* uw = (const float*)d_in[3];
  const float* dw = (const float*)d_in[4];
  float* out = (float*)d_out;

  char* ws = (char*)d_ws;
  int* counts = (int*)(ws + 0);
  int* cursor = (int*)(ws + 64);
  int* bases = (int*)(ws + 128);
  int* tok_i = (int*)(ws + 256);
  float* tok_w = (float*)(ws + 8448);
  int* slot_token = (int*)(ws + 16640);
  float* slot_w = (float*)(ws + 24832);
  int* slot_of = (int*)(ws + 33024);
  short* xg = (short*)(ws + 41216);             // 2048 x 1024 bf16
  short* m_buf = (short*)(ws + 4235520);        // 2048 x 2816 bf16
  float* out_slot = (float*)(ws + 15769856);    // 2048 x 1024 f32

  (void)hipMemsetAsync(counts, 0, 64, stream);
  router_kernel<<<NT, 64, 0, stream>>>(x, rw, counts, tok_i, tok_w);
  scan_kernel<<<1, 64, 0, stream>>>(counts, bases, cursor);
  fill_kernel<<<NT / 256, 256, 0, stream>>>(tok_i, tok_w, cursor, slot_token,
                                            slot_w, slot_of);
  gather_kernel<<<NSLOT, 256, 0, stream>>>(x, slot_token, xg);
  gateup_kernel<<<dim3(352, 16), 256, 0, stream>>>(xg, gw, uw, bases, m_buf);
  down_kernel<<<dim3(128, 32), 256, 0, stream>>>(m_buf, dw, bases, slot_w,
                                                 out_slot);
  combine_kernel<<<NT, 256, 0, stream>>>(out_slot, slot_of, out);
}